// Round 1
// 1745.125 us; speedup vs baseline: 1.1012x; 1.1012x over previous
//
#include <hip/hip_runtime.h>

// Gamma-smoothed forward-backward chain marginals, B=4 K=21 H=W=256.
// Linear-space recurrence; scale factor from per-step rescale cancels in the
// final per-k normalization done by the combine kernel (so fast rcp is exact
// enough). Scan writes unnormalized ea (fwd) then ea*eb (bwd) into mh/mv
// regions of d_out; combine normalizes and emits all 4 outputs.

#define K 21
#define KP 22             // padded LDS row
#define TT 16             // w-tile edges (full 64B line per staged row)
#define HP 256
#define NE 255
#define ROWF (K*KP)       // 462
#define TILEF (TT*ROWF)   // 7392
#define EUF (TT*K)        // 336
#define NT 16             // ceil(255/16)
#define NP (K*K*TT)       // 7056 P elements per tile
#define SZ (4*K*HP*HP)    // 5505024 floats per output tensor
#define KS4 261120u       // NE*HP*4 bytes: per-row stride in ph, per-kp stride in pv
#define KS4K 5483520u     // KS4*K: per-k (outer) stride in pv

__device__ __forceinline__ float rlane(float v, int l) {
  return __int_as_float(__builtin_amdgcn_readlane(__float_as_int(v), l));
}
__device__ __forceinline__ float ldu(const float* p, unsigned off) {
  return *(const float*)((const char*)p + off);
}
__device__ __forceinline__ void stu(float* p, unsigned off, float v) {
  *(float*)((char*)p + off) = v;
}

__global__ __launch_bounds__(384)
void fp_scan_kernel(const float* __restrict__ uh, const float* __restrict__ uv,
                    const float* __restrict__ ph, const float* __restrict__ pv,
                    const float* __restrict__ gam, float* out) {
  __shared__ float smem[2*TILEF + 2*EUF];   // 61824 B; v-path uses first 672 floats
  const float g  = fmaxf(gam[0], 0.01f);
  const float c2 = 1.44269504088896341f / g;   // log2(e)/g : exp(x/g) == exp2(x*c2)
  float* outMH = out + 2L*SZ;
  float* outMV = out + 3L*SZ;
  const int wg = blockIdx.x;
  const int tid = threadIdx.x;

  if (wg < 64) {
    // ================= vertical chains: 16 chains/wg, coalesced direct loads ==========
    const int b   = wg >> 4;
    const int wc0 = (wg & 15) << 4;
    const int kIdx = tid >> 4;             // 0..23 (>=21 are clamped dups)
    const int c    = tid & 15;             // chain within group
    const int kk   = (kIdx < K) ? kIdx : (K-1);
    const bool pred = (kIdx < K);
    float* bc = smem;                      // 2 x 336 broadcast buffers

    const unsigned uB4 = ((unsigned)((b*K + kk)*HP)*HP + wc0 + c) * 4u;  // + i*1024
    float pA[K], pB[K];

    // ---------- forward ----------
    {
      const unsigned pf4 = ((unsigned)(b*K*K + kk)*(NE*HP) + wc0 + c) * 4u;  // (b,0,kk,0,w)
      float ea = exp2f(ldu(uv, uB4) * c2);
      if (pred) stu(outMV, uB4, ea);
      #pragma unroll
      for (int k2 = 0; k2 < K; ++k2) pA[k2] = ldu(pv, pf4 + (unsigned)k2*KS4K);
      float uA = ldu(uv, uB4 + 1024u), uB;

      auto fstep = [&](int i, const float* P, float uN, float ea_) -> float {
        bc[(i&1)*336 + kk*16 + c] = ea_;
        __syncthreads();
        const float* bb = bc + (i&1)*336 + c;
        float y0 = fmaxf(bb[0], 1e-33f);
        float s0=0.f, s1=0.f, s2=0.f;
        #pragma unroll
        for (int k2 = 0; k2 < K; k2 += 3) {
          s0 = fmaf(exp2f(P[k2  ]*c2), bb[(k2  )*16], s0);
          s1 = fmaf(exp2f(P[k2+1]*c2), bb[(k2+1)*16], s1);
          s2 = fmaf(exp2f(P[k2+2]*c2), bb[(k2+2)*16], s2);
        }
        float r = (((s0+s1)+s2) * __builtin_amdgcn_rcpf(y0)) * exp2f(uN*c2);
        if (pred) stu(outMV, uB4 + (unsigned)(i+1)*1024u, r);
        return r;
      };

      for (int i = 0; i < 254; i += 2) {          // depth-2 register prefetch
        const unsigned o1 = pf4 + (unsigned)(i+1)*1024u;
        #pragma unroll
        for (int k2=0;k2<K;++k2) pB[k2] = ldu(pv, o1 + (unsigned)k2*KS4K);
        uB = ldu(uv, uB4 + (unsigned)(i+2)*1024u);
        ea = fstep(i, pA, uA, ea);
        const unsigned o2 = pf4 + (unsigned)(i+2)*1024u;
        #pragma unroll
        for (int k2=0;k2<K;++k2) pA[k2] = ldu(pv, o2 + (unsigned)k2*KS4K);
        uA = ldu(uv, uB4 + (unsigned)(i+3)*1024u);
        ea = fstep(i+1, pB, uB, ea);
      }
      ea = fstep(254, pA, uA, ea);
    }
    __syncthreads();
    // ---------- backward ----------
    {
      const unsigned pb4 = ((unsigned)((b*K + kk)*K)*(NE*HP) + wc0 + c) * 4u; // (b,kk,0,i,w)
      float eb = 1.0f;
      #pragma unroll
      for (int k2=0;k2<K;++k2) pA[k2] = ldu(pv, pb4 + (unsigned)k2*KS4 + 254u*1024u);
      float uA  = ldu(uv, uB4 + 255u*1024u), uB;
      float eaA = ldu(outMV, uB4 + 254u*1024u), eaB;

      auto bstep = [&](int i, const float* P, float uN, float eaP, float eb_) -> float {
        float y = eb_ * exp2f(uN*c2);
        bc[(i&1)*336 + kk*16 + c] = y;
        __syncthreads();
        const float* bb = bc + (i&1)*336 + c;
        float y0 = fmaxf(bb[0], 1e-33f);
        float s0=0.f, s1=0.f, s2=0.f;
        #pragma unroll
        for (int k2 = 0; k2 < K; k2 += 3) {
          s0 = fmaf(exp2f(P[k2  ]*c2), bb[(k2  )*16], s0);
          s1 = fmaf(exp2f(P[k2+1]*c2), bb[(k2+1)*16], s1);
          s2 = fmaf(exp2f(P[k2+2]*c2), bb[(k2+2)*16], s2);
        }
        float r = ((s0+s1)+s2) * __builtin_amdgcn_rcpf(y0);
        if (pred) stu(outMV, uB4 + (unsigned)i*1024u, eaP * r);   // unnormalized ea*eb
        return r;
      };

      for (int i = 254; i >= 2; i -= 2) {
        const unsigned o1 = pb4 + (unsigned)(i-1)*1024u;
        #pragma unroll
        for (int k2=0;k2<K;++k2) pB[k2] = ldu(pv, o1 + (unsigned)k2*KS4);
        uB  = ldu(uv, uB4 + (unsigned)i*1024u);
        eaB = ldu(outMV, uB4 + (unsigned)(i-1)*1024u);
        eb = bstep(i, pA, uA, eaA, eb);
        const int im2 = (i-2>0)?(i-2):0;
        const unsigned o2 = pb4 + (unsigned)im2*1024u;
        #pragma unroll
        for (int k2=0;k2<K;++k2) pA[k2] = ldu(pv, o2 + (unsigned)k2*KS4);
        uA  = ldu(uv, uB4 + (unsigned)(i-1)*1024u);
        eaA = ldu(outMV, uB4 + (unsigned)im2*1024u);
        eb = bstep(i-1, pB, uB, eaB, eb);
      }
      eb = bstep(0, pA, uA, eaA, eb);
    }
  } else {
    // ================= horizontal chains: 1 chain/wg, LDS double-buffered tiles ======
    const int id = wg - 64;
    const int b = id >> 8;
    const int h = id & 255;
    const int lane   = tid & 63;
    const int waveId = tid >> 6;
    const int stid   = tid - 64;                  // staging thread id (waves 1..5)
    const int cc  = (lane < K) ? lane : (K-1);
    const bool act = (lane < K) && (waveId == 0);
    float* EuBase = smem + 2*TILEF;

    const unsigned phB = (unsigned)(b*(K*K))*KS4 + (unsigned)(h*NE)*4u;  // + row*KS4 + w*4
    const unsigned uhB = (unsigned)(b*K*HP + h)*(HP*4u);                 // + kk2*HP*HP*4 + pos*4

    // Two-phase staging: issue all 25 independent loads first (deep MLP),
    // then exp + LDS write. phase 0: [t][k'][k]; phase 1: [t][k][k'].
    auto stage = [&](int it, int phase) {
      float* Pb = smem  + (it & 1)*TILEF;
      float* Eb = EuBase + (it & 1)*EUF;
      const int w0 = it * TT;
      float vP[23], vE0, vE1;
      #pragma unroll
      for (int j = 0; j < 23; ++j) {
        int idx = stid + j*320;
        idx = (idx < NP) ? idx : (NP-1);          // folds for j<22
        int row = idx >> 4, t = idx & 15;
        int w = w0 + t; w = (w < NE) ? w : (NE-1);
        vP[j] = ldu(ph, phB + (unsigned)row*KS4 + (unsigned)w*4u);
      }
      {
        int r0 = (stid < EUF) ? stid : (EUF-1);
        int p0 = w0 + 1 + (r0 & 15); p0 = (p0 < HP) ? p0 : (HP-1);
        vE0 = ldu(uh, uhB + (unsigned)(r0 >> 4)*(HP*HP*4u) + (unsigned)p0*4u);
        int r1 = (stid + 320 < EUF) ? (stid + 320) : (EUF-1);
        int p1 = w0 + 1 + (r1 & 15); p1 = (p1 < HP) ? p1 : (HP-1);
        vE1 = ldu(uh, uhB + (unsigned)(r1 >> 4)*(HP*HP*4u) + (unsigned)p1*4u);
      }
      #pragma unroll
      for (int j = 0; j < 23; ++j) {
        int idx = stid + j*320;
        if (idx < NP) {
          float e = exp2f(vP[j] * c2);
          int row = idx >> 4, t = idx & 15;
          int k = row / K, kp = row - k*K;
          int a  = phase ? k : kp;
          int b2 = phase ? kp : k;
          Pb[t*ROWF + a*KP + b2] = e;
        }
      }
      if (stid < EUF) Eb[(stid & 15)*K + (stid >> 4)] = exp2f(vE0 * c2);
      {
        int r1 = stid + 320;
        if (r1 < EUF) Eb[(r1 & 15)*K + (r1 >> 4)] = exp2f(vE1 * c2);
      }
    };

    const unsigned chB = (unsigned)((b*K + cc)*HP + h)*(HP*4u);   // + w*4

    // ---------- forward ----------
    float ea = 0.f;
    if (waveId == 0) {
      ea = exp2f(ldu(uh, chB) * c2);             // position 0
      if (act) stu(outMH, chB, ea);
    }
    if (waveId > 0) stage(0, 0);
    __syncthreads();
    for (int it = 0; it < NT; ++it) {
      if (waveId > 0) {
        if (it + 1 < NT) stage(it + 1, 0);
      } else {
        float* Pb = smem  + (it & 1)*TILEF;
        float* Eb = EuBase + (it & 1)*EUF;
        const int w0 = it * TT;
        const int tt = min(TT, NE - w0);
        for (int t = 0; t < tt; ++t) {
          const float* row = Pb + t*ROWF + cc*KP;
          float s0=0.f, s1=0.f, s2=0.f;
          #pragma unroll
          for (int k2 = 0; k2 < K; k2 += 3) {
            s0 = fmaf(row[k2  ], rlane(ea, k2  ), s0);
            s1 = fmaf(row[k2+1], rlane(ea, k2+1), s1);
            s2 = fmaf(row[k2+2], rlane(ea, k2+2), s2);
          }
          float v  = ((s0+s1)+s2) * Eb[t*K + cc];
          float v0 = fmaxf(rlane(v, 0), 1e-33f);
          ea = v * __builtin_amdgcn_rcpf(v0);
          if (act) stu(outMH, chB + (unsigned)(w0 + t + 1)*4u, ea);
        }
      }
      __syncthreads();
    }
    // ---------- backward ----------
    float eb = 1.0f;
    float eaPref = 0.f;
    if (waveId == 0) eaPref = ldu(outMH, chB + (unsigned)(NE-1)*4u);   // ea at pos 254
    if (waveId > 0) stage(NT-1, 1);
    __syncthreads();
    for (int it = NT-1; it >= 0; --it) {
      if (waveId > 0) {
        if (it > 0) stage(it - 1, 1);
      } else {
        float* Pb = smem  + (it & 1)*TILEF;
        float* Eb = EuBase + (it & 1)*EUF;
        const int w0 = it * TT;
        const int tt = min(TT, NE - w0);
        for (int t = tt - 1; t >= 0; --t) {
          float y = eb * Eb[t*K + cc];
          const float* row = Pb + t*ROWF + cc*KP;
          float s0=0.f, s1=0.f, s2=0.f;
          #pragma unroll
          for (int k2 = 0; k2 < K; k2 += 3) {
            s0 = fmaf(row[k2  ], rlane(y, k2  ), s0);
            s1 = fmaf(row[k2+1], rlane(y, k2+1), s1);
            s2 = fmaf(row[k2+2], rlane(y, k2+2), s2);
          }
          float s  = (s0+s1)+s2;
          float v0 = fmaxf(rlane(s, 0), 1e-33f);
          eb = s * __builtin_amdgcn_rcpf(v0);
          float prod = eaPref * eb;
          int pos = w0 + t;
          eaPref = ldu(outMH, chB + (unsigned)max(pos - 1, 0)*4u);   // prefetch next
          if (act) stu(outMH, chB + (unsigned)pos*4u, prod);
        }
      }
      __syncthreads();
    }
  }
}

__global__ __launch_bounds__(256)
void fp_combine_kernel(const float* __restrict__ uh, const float* __restrict__ uv,
                       float* __restrict__ out) {
  const int lin = blockIdx.x * 256 + threadIdx.x;   // B*H*W = 262144 exactly
  const int b   = lin >> 16;
  const int rem = lin & 65535;                       // h*256 + w
  const long base = (long)b * K * 65536 + rem;
  const long KS = 65536;
  float mh[K], mv[K];
  float smh = 0.f, smv = 0.f;
  #pragma unroll
  for (int k = 0; k < K; ++k) {
    mh[k] = out[2L*SZ + base + k*KS];
    mv[k] = out[3L*SZ + base + k*KS];
    smh += mh[k]; smv += mv[k];
  }
  const float rh = 1.0f / smh, rv = 1.0f / smv;
  #pragma unroll
  for (int k = 0; k < K; ++k) {
    float a  = mh[k] * rh;        // normalized mh
    float vv = mv[k] * rv;        // normalized mv
    float d  = (a - vv) * (1.0f / 512.0f);   // (mh-avg)/W = (mh-mv)/(2*256)
    out[        base + k*KS] = uh[base + k*KS] - d;
    out[1L*SZ + base + k*KS] = uv[base + k*KS] + d;
    out[2L*SZ + base + k*KS] = a;
    out[3L*SZ + base + k*KS] = vv;
  }
}

extern "C" void kernel_launch(void* const* d_in, const int* in_sizes, int n_in,
                              void* d_out, int out_size, void* d_ws, size_t ws_size,
                              hipStream_t stream) {
  const float* uh = (const float*)d_in[0];
  const float* uv = (const float*)d_in[1];
  const float* ph = (const float*)d_in[2];
  const float* pv = (const float*)d_in[3];
  const float* gm = (const float*)d_in[4];
  float* out = (float*)d_out;
  hipLaunchKernelGGL(fp_scan_kernel,    dim3(1088), dim3(384), 0, stream, uh, uv, ph, pv, gm, out);
  hipLaunchKernelGGL(fp_combine_kernel, dim3(1024), dim3(256), 0, stream, uh, uv, out);
}